// Round 3
// baseline (653.802 us; speedup 1.0000x reference)
//
#include <hip/hip_runtime.h>
#include <math.h>

// VQ-VAE VectorQuantizer forward:
//   x: [64,32,32,64] f32 -> N=65536 points, D=64
//   E: [D=64, K=1024] f32 (row-major: E[d*K + k])
// Outputs concatenated flat (float32):
//   quantized_st [N*D] | loss [1] | perplexity [1] | encoding_indices [N] (as float)
//
// The checker's np reference computes distance in FLOAT32 per the literal
// formula  ||f||^2 - 2 f@E + ||e||^2  (magnitude ~65 -> ulp ~7.6e-6), so
// near-tied codes can EXACTLY tie in fp32 and argmax(-d) picks the lowest k.
// We therefore gate: fast fp32 scan (no ||f||^2 term) finds top-3; when the
// top-2 gap is inside fp32-ambiguity we re-evaluate candidates with emulated
// reference arithmetic (__f*_rn to defeat fp contraction) and first-occurrence
// tie-break in ascending k.

constexpr int D = 64;
constexpr int K = 1024;
constexpr int NPTS = 65536;
constexpr long QOFF = (long)NPTS * D;  // 4194304

// ws layout: [double lossSum][int counts[K]][float eC[K]]
constexpr size_t WS_LOSS_OFF = 0;
constexpr size_t WS_CNT_OFF = 8;
constexpr size_t WS_ENORM_OFF = 8 + (size_t)K * 4;
constexpr size_t WS_ZERO_BYTES = 8 + (size_t)K * 4;  // loss + counts need zeroing

// ||e_k||^2 in the np reference's order: np.sum(E**2, axis=0) reduces the
// OUTER axis -> sequential accumulation over d ascending, fp32 each step.
__global__ __launch_bounds__(256) void enorm_kernel(const float* __restrict__ E,
                                                    float* __restrict__ eC) {
  int k = blockIdx.x * 256 + threadIdx.x;  // coalesced: lane k reads E[d*K + k]
  float c = __fmul_rn(E[k], E[k]);
#pragma unroll
  for (int d = 1; d < D; ++d) {
    float v = E[d * K + k];
    c = __fadd_rn(c, __fmul_rn(v, v));
  }
  eC[k] = c;
}

__global__ __launch_bounds__(256) void vq_main(const float* __restrict__ x,
                                               const float* __restrict__ E,
                                               const float* __restrict__ eC,
                                               float* __restrict__ out,
                                               double* __restrict__ lossSum,
                                               int* __restrict__ counts) {
  const int p = blockIdx.x * 256 + threadIdx.x;

  // Load this point's feature vector into registers (16 x float4 per lane).
  float f[D];
  const float4* xv = reinterpret_cast<const float4*>(x + (size_t)p * D);
#pragma unroll
  for (int i = 0; i < D / 4; ++i) {
    float4 v = xv[i];
    f[4 * i + 0] = v.x;
    f[4 * i + 1] = v.y;
    f[4 * i + 2] = v.z;
    f[4 * i + 3] = v.w;
  }

  // Fast argmin scan of  ||e_k||^2 - 2 f.e_k  (same argmin as full distance),
  // tracking top-3 so ambiguous points can be re-resolved in ref arithmetic.
  float best1 = __builtin_inff(), best2 = __builtin_inff(), best3 = __builtin_inff();
  int k1 = 0, k2 = 0, k3 = 0;
  for (int k0 = 0; k0 < K; k0 += 8) {
    float acc[8];
#pragma unroll
    for (int j = 0; j < 8; ++j) acc[j] = 0.f;
#pragma unroll 4
    for (int d = 0; d < D; ++d) {
      const float fd = f[d];
      const float* __restrict__ erow = E + d * K + k0;  // wave-uniform addr
#pragma unroll
      for (int j = 0; j < 8; ++j) acc[j] = fmaf(fd, erow[j], acc[j]);
    }
#pragma unroll
    for (int j = 0; j < 8; ++j) {
      float dist = fmaf(-2.f, acc[j], eC[k0 + j]);
      if (dist < best1) {  // strict <: first-occurrence min
        best3 = best2; k3 = k2;
        best2 = best1; k2 = k1;
        best1 = dist;  k1 = k0 + j;
      } else if (dist < best2) {
        best3 = best2; k3 = k2;
        best2 = dist;  k2 = k0 + j;
      } else if (dist < best3) {
        best3 = dist;  k3 = k0 + j;
      }
    }
  }

  int bestk = k1;
  // Ambiguity gate: ref's fp32 distance error is ~5e-5 abs; if the fast top-2
  // gap is within 2e-4, re-resolve with emulated reference arithmetic.
  if (best2 - best1 < 2e-4f) {
    // A = np.sum(f**2) over contiguous axis: numpy pairwise-8 pattern.
    float r[8];
#pragma unroll
    for (int j = 0; j < 8; ++j) r[j] = __fmul_rn(f[j], f[j]);
#pragma unroll
    for (int i = 8; i < D; i += 8)
#pragma unroll
      for (int j = 0; j < 8; ++j) r[j] = __fadd_rn(r[j], __fmul_rn(f[i + j], f[i + j]));
    float A = __fadd_rn(__fadd_rn(__fadd_rn(r[0], r[1]), __fadd_rn(r[2], r[3])),
                        __fadd_rn(__fadd_rn(r[4], r[5]), __fadd_rn(r[6], r[7])));

    // Candidates in ascending k (first-occurrence tie-break like argmax(-d)).
    int c0 = k1, c1 = k2, c2 = k3, t;
    if (c1 < c0) { t = c0; c0 = c1; c1 = t; }
    if (c2 < c1) { t = c1; c1 = c2; c2 = t; }
    if (c1 < c0) { t = c0; c0 = c1; c1 = t; }
    int cand[3] = {c0, c1, c2};

    float bd = __builtin_inff();
    int bk = c0;
#pragma unroll
    for (int c = 0; c < 3; ++c) {
      int k = cand[c];
      // M = (f @ E)[k]: BLAS sgemm k-loop = sequential fp32 fma over d.
      float m = 0.f;
#pragma unroll 4
      for (int d = 0; d < D; ++d) m = __fmaf_rn(f[d], E[d * K + k], m);
      // dist = fl32( fl32(A - fl32(2*m)) + C )  (python left-to-right order)
      float dist = __fadd_rn(__fsub_rn(A, __fmul_rn(2.f, m)), eC[k]);
      if (dist < bd) { bd = dist; bk = k; }  // strict <: lower k wins ties
    }
    bestk = bk;
  }

  // Gather chosen code, write quantized (= quantized_st numerically), accumulate
  // squared error for the loss.
  float errs = 0.f;
  float4* ov = reinterpret_cast<float4*>(out + (size_t)p * D);
#pragma unroll
  for (int i = 0; i < D / 4; ++i) {
    float4 q;
    q.x = E[(4 * i + 0) * K + bestk];
    q.y = E[(4 * i + 1) * K + bestk];
    q.z = E[(4 * i + 2) * K + bestk];
    q.w = E[(4 * i + 3) * K + bestk];
    float dx;
    dx = q.x - f[4 * i + 0]; errs = fmaf(dx, dx, errs);
    dx = q.y - f[4 * i + 1]; errs = fmaf(dx, dx, errs);
    dx = q.z - f[4 * i + 2]; errs = fmaf(dx, dx, errs);
    dx = q.w - f[4 * i + 3]; errs = fmaf(dx, dx, errs);
    ov[i] = q;
  }

  // encoding index (exact as float for k < 2^24)
  out[QOFF + 2 + p] = (float)bestk;

  // histogram for perplexity
  atomicAdd(&counts[bestk], 1);

  // wave-level reduction of squared error, one double atomic per wave
  double de = (double)errs;
#pragma unroll
  for (int off = 32; off > 0; off >>= 1) de += __shfl_down(de, off, 64);
  if ((threadIdx.x & 63) == 0) atomicAdd(lossSum, de);
}

__global__ __launch_bounds__(256) void vq_finalize(const double* __restrict__ lossSum,
                                                   const int* __restrict__ counts,
                                                   float* __restrict__ out) {
  __shared__ double sh[256];
  double ent = 0.0;
  for (int k = threadIdx.x; k < K; k += 256) {
    double pp = (double)counts[k] / (double)NPTS;
    ent += pp * log(pp + 1e-10);
  }
  sh[threadIdx.x] = ent;
  __syncthreads();
  for (int s = 128; s > 0; s >>= 1) {
    if (threadIdx.x < s) sh[threadIdx.x] += sh[threadIdx.x + s];
    __syncthreads();
  }
  if (threadIdx.x == 0) {
    // loss = q_latent + 0.25 * e_latent = 1.25 * mean((q - x)^2)
    out[QOFF + 0] = (float)(1.25 * (*lossSum) / (double)((long)NPTS * D));
    out[QOFF + 1] = (float)exp(-sh[0]);  // perplexity
  }
}

extern "C" void kernel_launch(void* const* d_in, const int* in_sizes, int n_in,
                              void* d_out, int out_size, void* d_ws, size_t ws_size,
                              hipStream_t stream) {
  const float* x = (const float*)d_in[0];
  const float* E = (const float*)d_in[1];
  float* out = (float*)d_out;

  double* lossSum = (double*)((char*)d_ws + WS_LOSS_OFF);
  int* counts = (int*)((char*)d_ws + WS_CNT_OFF);
  float* eC = (float*)((char*)d_ws + WS_ENORM_OFF);

  // ws is poisoned 0xAA before every timed launch — zero what we accumulate into.
  hipMemsetAsync(d_ws, 0, WS_ZERO_BYTES, stream);

  enorm_kernel<<<K / 256, 256, 0, stream>>>(E, eC);
  vq_main<<<NPTS / 256, 256, 0, stream>>>(x, E, eC, out, lossSum, counts);
  vq_finalize<<<1, 256, 0, stream>>>(lossSum, counts, out);
}

// Round 4
// 353.912 us; speedup vs baseline: 1.8474x; 1.8474x over previous
//
#include <hip/hip_runtime.h>
#include <math.h>

// VQ-VAE VectorQuantizer forward:
//   x: [64,32,32,64] f32 -> N=65536 points, D=64
//   E: [D=64, K=1024] f32 (row-major: E[d*K + k])
// Outputs concatenated flat (float32):
//   quantized_st [N*D] | loss [1] | perplexity [1] | encoding_indices [N] (as float)
//
// Structure (round 4): block = 256 threads = 4 waves handles 64 points.
//   wave w scans K-chunk [w*256, w*256+256) for all 64 points (lane = point).
//   E addresses are wave-uniform -> s_load; f[64] register-resident (full unroll).
//   Per-thread top-6 via v_med3 insert on bias-packed dists (index in low 8
//   mantissa bits -> ties auto-break to lower k). LDS merge across chunks,
//   then the round-3-proven fp32-reference-emulating refinement for gated
//   ambiguous points. Epilogue: 4 threads/point coalesced writes.

constexpr int D = 64;
constexpr int K = 1024;
constexpr int NPTS = 65536;
constexpr long QOFF = (long)NPTS * D;  // 4194304
constexpr float BIAS = 24.0f;          // fast-dist in [-23,24] -> biased (1,48): positive
constexpr float GATE = 2e-3f;          // ref err (~2e-4) + 2x pack err (~5e-4) + margin

// ws layout: [double lossSum][int counts[K]][float eC[K]][float eCb[K]]
constexpr size_t WS_LOSS_OFF = 0;
constexpr size_t WS_CNT_OFF = 8;
constexpr size_t WS_ENORM_OFF = 8 + (size_t)K * 4;
constexpr size_t WS_ENORMB_OFF = WS_ENORM_OFF + (size_t)K * 4;
constexpr size_t WS_ZERO_BYTES = 8 + (size_t)K * 4;  // loss + counts need zeroing

__device__ __forceinline__ float med3(float a, float b, float c) {
  return __builtin_amdgcn_fmed3f(a, b, c);
}

// ||e_k||^2 in the np reference's order: np.sum(E**2, axis=0) reduces the
// OUTER axis -> sequential fp32 accumulation over d ascending (round-3 exact).
__global__ __launch_bounds__(256) void enorm_kernel(const float* __restrict__ E,
                                                    float* __restrict__ eC,
                                                    float* __restrict__ eCb) {
  int k = blockIdx.x * 256 + threadIdx.x;
  float c = __fmul_rn(E[k], E[k]);
#pragma unroll
  for (int d = 1; d < D; ++d) {
    float v = E[d * K + k];
    c = __fadd_rn(c, __fmul_rn(v, v));
  }
  eC[k] = c;
  eCb[k] = c + BIAS;  // biased copy for the packed fast scan
}

__global__ __launch_bounds__(256) void vq_main(const float* __restrict__ x,
                                               const float* __restrict__ E,
                                               const float* __restrict__ eC,
                                               const float* __restrict__ eCb,
                                               float* __restrict__ out,
                                               double* __restrict__ lossSum,
                                               int* __restrict__ counts) {
  __shared__ float tops[64 * 25];  // [point][chunk*6 + r], stride 25 (pad)
  __shared__ int bk_lds[64];

  const int tid = threadIdx.x;
  const int lane = tid & 63;                                     // point-in-block
  const int q = __builtin_amdgcn_readfirstlane(tid >> 6);        // K-chunk (wave id)
  const int pbase = blockIdx.x * 64;
  const int p = pbase + lane;

  // ---- load this point's feature vector into registers (16 x float4) ----
  float f[D];
  const float4* xv = reinterpret_cast<const float4*>(x + (size_t)p * D);
#pragma unroll
  for (int i = 0; i < D / 4; ++i) {
    float4 v = xv[i];
    f[4 * i + 0] = v.x;
    f[4 * i + 1] = v.y;
    f[4 * i + 2] = v.z;
    f[4 * i + 3] = v.w;
  }

  // ---- fast scan of chunk [q*256, q*256+256): top-6 of packed biased dists ----
  // packed = float(eCb[k] - 2*f.e_k) with low 8 mantissa bits replaced by local k.
  float b1 = __builtin_inff(), b2 = __builtin_inff(), b3 = __builtin_inff();
  float b4 = __builtin_inff(), b5 = __builtin_inff(), b6 = __builtin_inff();
  const int qbase = q * 256;
  for (int k0 = 0; k0 < 256; k0 += 8) {
    float acc[8];
#pragma unroll
    for (int j = 0; j < 8; ++j) acc[j] = 0.f;
    const float* __restrict__ ecol = E + qbase + k0;  // wave-uniform
#pragma unroll
    for (int d = 0; d < D; ++d) {  // FULL unroll: f[] stays in VGPRs
      const float fd = f[d];
      const float* __restrict__ erow = ecol + d * K;
#pragma unroll
      for (int j = 0; j < 8; ++j) acc[j] = fmaf(fd, erow[j], acc[j]);
    }
    const float* __restrict__ ecrow = eCb + qbase + k0;  // wave-uniform
#pragma unroll
    for (int j = 0; j < 8; ++j) {
      float dist = fmaf(-2.f, acc[j], ecrow[j]);  // biased, positive
      unsigned u = (__float_as_uint(dist) & ~255u) | (unsigned)(k0 + j);
      float v = __uint_as_float(u);
      float p1 = b1, p2 = b2, p3 = b3, p4 = b4, p5 = b5;
      b1 = fminf(b1, v);
      b2 = med3(p1, p2, v);
      b3 = med3(p2, p3, v);
      b4 = med3(p3, p4, v);
      b5 = med3(p4, p5, v);
      b6 = med3(p5, b6, v);
    }
  }

  // ---- stash per-chunk top-6 in LDS ----
  float* myrow = tops + lane * 25 + q * 6;
  myrow[0] = b1; myrow[1] = b2; myrow[2] = b3;
  myrow[3] = b4; myrow[4] = b5; myrow[5] = b6;
  __syncthreads();

  // ---- merge + gated ref-exact refinement (threads 0..63, one per point) ----
  if (tid < 64) {
    float mv[6]; int mk[6];
#pragma unroll
    for (int r = 0; r < 6; ++r) { mv[r] = __builtin_inff(); mk[r] = 0; }
    const float* row = tops + tid * 25;
#pragma unroll
    for (int qq = 0; qq < 4; ++qq) {
#pragma unroll
      for (int r = 0; r < 6; ++r) {
        float v = row[qq * 6 + r];
        int gk = qq * 256 + (int)(__float_as_uint(v) & 255u);
        // predicated insert into sorted top-6 (strict <: earlier/lower-k wins ties)
        bool c0 = v < mv[0], c1 = v < mv[1], c2 = v < mv[2];
        bool c3 = v < mv[3], c4 = v < mv[4], c5 = v < mv[5];
        mv[5] = c4 ? mv[4] : (c5 ? v : mv[5]); mk[5] = c4 ? mk[4] : (c5 ? gk : mk[5]);
        mv[4] = c3 ? mv[3] : (c4 ? v : mv[4]); mk[4] = c3 ? mk[3] : (c4 ? gk : mk[4]);
        mv[3] = c2 ? mv[2] : (c3 ? v : mv[3]); mk[3] = c2 ? mk[2] : (c3 ? gk : mk[3]);
        mv[2] = c1 ? mv[1] : (c2 ? v : mv[2]); mk[2] = c1 ? mk[1] : (c2 ? gk : mk[2]);
        mv[1] = c0 ? mv[0] : (c1 ? v : mv[1]); mk[1] = c0 ? mk[0] : (c1 ? gk : mk[1]);
        mv[0] = c0 ? v : mv[0];                mk[0] = c0 ? gk : mk[0];
      }
    }

    int bestk = mk[0];
    if (mv[1] - mv[0] < GATE) {
      // ----- emulate the np reference's fp32 arithmetic exactly (round-3 proven) -----
      // A = np.sum(f**2) (pairwise-8 pattern)
      float r8[8];
#pragma unroll
      for (int j = 0; j < 8; ++j) r8[j] = __fmul_rn(f[j], f[j]);
#pragma unroll
      for (int i = 8; i < D; i += 8)
#pragma unroll
        for (int j = 0; j < 8; ++j) r8[j] = __fadd_rn(r8[j], __fmul_rn(f[i + j], f[i + j]));
      float A = __fadd_rn(__fadd_rn(__fadd_rn(r8[0], r8[1]), __fadd_rn(r8[2], r8[3])),
                          __fadd_rn(__fadd_rn(r8[4], r8[5]), __fadd_rn(r8[6], r8[7])));
      float bd = __builtin_inff();
      int bkk = K;
#pragma unroll
      for (int c = 0; c < 6; ++c) {
        int k = mk[c];
        float m = 0.f;  // sequential fp32 fma over d (BLAS k-loop order)
#pragma unroll
        for (int d = 0; d < D; ++d) m = __fmaf_rn(f[d], E[d * K + k], m);
        float dist = __fadd_rn(__fsub_rn(A, __fmul_rn(2.f, m)), eC[k]);
        // exact order-independent argmin with lowest-k tie-break
        bool better = (dist < bd) || (dist == bd && k < bkk);
        bd = better ? dist : bd;
        bkk = better ? k : bkk;
      }
      bestk = bkk;
    }

    bk_lds[tid] = bestk;
    out[QOFF + 2 + pbase + tid] = (float)bestk;  // index (exact as float)
    atomicAdd(&counts[bestk], 1);
  }
  __syncthreads();

  // ---- epilogue: 4 threads per point write quantized + accumulate loss ----
  const int ep = pbase + (tid >> 2);       // point
  const int part = tid & 3;                // 16 floats each
  const int bk = bk_lds[tid >> 2];
  float errs = 0.f;
  float4* ov = reinterpret_cast<float4*>(out + (size_t)ep * D + part * 16);
  const float4* xr = reinterpret_cast<const float4*>(x + (size_t)ep * D + part * 16);
#pragma unroll
  for (int i = 0; i < 4; ++i) {
    const int d0 = part * 16 + i * 4;
    float4 qv;
    qv.x = E[(d0 + 0) * K + bk];
    qv.y = E[(d0 + 1) * K + bk];
    qv.z = E[(d0 + 2) * K + bk];
    qv.w = E[(d0 + 3) * K + bk];
    float4 xv4 = xr[i];
    float dx;
    dx = qv.x - xv4.x; errs = fmaf(dx, dx, errs);
    dx = qv.y - xv4.y; errs = fmaf(dx, dx, errs);
    dx = qv.z - xv4.z; errs = fmaf(dx, dx, errs);
    dx = qv.w - xv4.w; errs = fmaf(dx, dx, errs);
    ov[i] = qv;
  }
  double de = (double)errs;
#pragma unroll
  for (int off = 32; off > 0; off >>= 1) de += __shfl_down(de, off, 64);
  if ((tid & 63) == 0) atomicAdd(lossSum, de);
}

__global__ __launch_bounds__(256) void vq_finalize(const double* __restrict__ lossSum,
                                                   const int* __restrict__ counts,
                                                   float* __restrict__ out) {
  __shared__ double sh[256];
  double ent = 0.0;
  for (int k = threadIdx.x; k < K; k += 256) {
    double pp = (double)counts[k] / (double)NPTS;
    ent += pp * log(pp + 1e-10);
  }
  sh[threadIdx.x] = ent;
  __syncthreads();
  for (int s = 128; s > 0; s >>= 1) {
    if (threadIdx.x < s) sh[threadIdx.x] += sh[threadIdx.x + s];
    __syncthreads();
  }
  if (threadIdx.x == 0) {
    // loss = q_latent + 0.25 * e_latent = 1.25 * mean((q - x)^2)
    out[QOFF + 0] = (float)(1.25 * (*lossSum) / (double)((long)NPTS * D));
    out[QOFF + 1] = (float)exp(-sh[0]);  // perplexity
  }
}

extern "C" void kernel_launch(void* const* d_in, const int* in_sizes, int n_in,
                              void* d_out, int out_size, void* d_ws, size_t ws_size,
                              hipStream_t stream) {
  const float* x = (const float*)d_in[0];
  const float* E = (const float*)d_in[1];
  float* out = (float*)d_out;

  double* lossSum = (double*)((char*)d_ws + WS_LOSS_OFF);
  int* counts = (int*)((char*)d_ws + WS_CNT_OFF);
  float* eC = (float*)((char*)d_ws + WS_ENORM_OFF);
  float* eCb = (float*)((char*)d_ws + WS_ENORMB_OFF);

  // ws is poisoned 0xAA before every timed launch — zero what we accumulate into.
  hipMemsetAsync(d_ws, 0, WS_ZERO_BYTES, stream);

  enorm_kernel<<<K / 256, 256, 0, stream>>>(E, eC, eCb);
  vq_main<<<NPTS / 64, 256, 0, stream>>>(x, E, eC, eCb, out, lossSum, counts);
  vq_finalize<<<1, 256, 0, stream>>>(lossSum, counts, out);
}

// Round 5
// 134.655 us; speedup vs baseline: 4.8554x; 2.6283x over previous
//
#include <hip/hip_runtime.h>
#include <math.h>

// VQ-VAE VectorQuantizer forward (MFMA bf16-split formulation):
//   x: [64,32,32,64] f32 -> N=65536 points, D=64
//   E: [D=64, K=1024] f32 (row-major: E[d*K + k])
// Outputs concatenated flat (float32):
//   quantized_st [N*D] | loss [1] | perplexity [1] | encoding_indices [N] (as float)
//
// Fast scan: dist_fast = ||e_k||^2 + BIAS - 2 f.e_k computed via MFMA:
//   C init = eCb[k], then C += Xh*(-2Eh) + Xh*(-2El) + Xl*(-2Eh)  (bf16 split,
//   lo*lo dropped; abs err ~5e-4). Index packed into low 8 mantissa bits.
// Gated points (top-2 gap < GATE) re-resolved with the round-3-proven exact
// emulation of the np reference's fp32 arithmetic (first-occurrence ties).

typedef __attribute__((ext_vector_type(8))) short short8v;
typedef __attribute__((ext_vector_type(4))) float float4v;
typedef unsigned short u16;
typedef unsigned int u32;

constexpr int D = 64;
constexpr int K = 1024;
constexpr int NPTS = 65536;
constexpr long QOFF = (long)NPTS * D;  // 4194304
constexpr float BIAS = 24.0f;
constexpr float GATE = 5e-3f;  // 2*(split 5e-4 + pack 1e-3) + ref err 2e-4 + margin

// ws layout (16B-aligned sections):
constexpr size_t OFF_LOSS = 0;                               // double
constexpr size_t OFF_CNT  = 256;                             // int[1024]
constexpr size_t OFF_EC   = OFF_CNT + 4096;                  // float[1024] ref-order norms
constexpr size_t OFF_ECB  = OFF_EC + 4096;                   // float[1024] norms + BIAS
constexpr size_t OFF_ET   = OFF_ECB + 4096;                  // float[1024*64] E transposed [k][d]
constexpr size_t OFF_H2   = OFF_ET + (size_t)K * D * 4;      // u16[1024*64] bf16 hi of -2E, [k][d]
constexpr size_t OFF_L2   = OFF_H2 + (size_t)K * D * 2;      // u16[1024*64] bf16 lo
constexpr size_t WS_ZERO  = OFF_CNT + 4096;                  // zero loss+counts

__device__ __forceinline__ float med3(float a, float b, float c) {
  return __builtin_amdgcn_fmed3f(a, b, c);
}
__device__ __forceinline__ u16 bf16rtn(float x) {
  u32 u = __float_as_uint(x);
  return (u16)((u + 0x7fffu + ((u >> 16) & 1u)) >> 16);
}
__device__ __forceinline__ float bf2f(u16 h) {
  return __uint_as_float(((u32)h) << 16);
}

// ||e_k||^2 in the np reference's order (sequential fp32 over d ascending).
__global__ __launch_bounds__(256) void prep_norm(const float* __restrict__ E,
                                                 float* __restrict__ eC,
                                                 float* __restrict__ eCb) {
  int k = blockIdx.x * 256 + threadIdx.x;
  float c = __fmul_rn(E[k], E[k]);
#pragma unroll
  for (int d = 1; d < D; ++d) {
    float v = E[d * K + k];
    c = __fadd_rn(c, __fmul_rn(v, v));
  }
  eC[k] = c;
  eCb[k] = c + BIAS;
}

// E -> Et (fp32 [k][d]) and -2E -> bf16 hi/lo split ([k][d]).
__global__ __launch_bounds__(256) void prep_conv(const float* __restrict__ E,
                                                 float* __restrict__ Et,
                                                 u16* __restrict__ h2,
                                                 u16* __restrict__ l2) {
  int gid = blockIdx.x * 256 + threadIdx.x;  // 16384 threads
  int k = gid & 1023;
  int dg = gid >> 10;  // 0..15
#pragma unroll
  for (int i = 0; i < 4; ++i) {
    int d = dg * 4 + i;
    float v = E[d * K + k];  // coalesced over k
    Et[(size_t)k * 64 + d] = v;
    float m2 = -2.0f * v;  // exact
    u16 h = bf16rtn(m2);
    u16 l = bf16rtn(m2 - bf2f(h));
    h2[(size_t)k * 64 + d] = h;
    l2[(size_t)k * 64 + d] = l;
  }
}

__global__ __launch_bounds__(256) void vq_main(const float* __restrict__ x,
                                               const float* __restrict__ E,
                                               const u16* __restrict__ h2g,
                                               const u16* __restrict__ l2g,
                                               const float* __restrict__ eC,
                                               const float* __restrict__ eCb,
                                               const float* __restrict__ Etg,
                                               float* __restrict__ out,
                                               double* __restrict__ lossSum,
                                               int* __restrict__ counts) {
  // LDS: E chunk (128 codes) hi/lo, row stride 72 u16 (144 B: 16B-aligned,
  // 2-way-free banks on A-frag reads), + chunk norms + merge buffers.
  __shared__ __align__(16) u16 hA[128 * 72];
  __shared__ __align__(16) u16 lA[128 * 72];
  __shared__ __align__(16) float ecb[128];
  __shared__ __align__(16) float topbuf[256 * 4];
  __shared__ int bkbuf[128];

  const int tid = threadIdx.x;
  const int w = tid >> 6;        // wave id: owns point-tiles 2w, 2w+1
  const int lane = tid & 63;
  const int col = lane & 15;     // A: code row; B: point col; C: point col
  const int quad = lane >> 4;    // k-group (A/B), row-group (C)
  const int blockBase = blockIdx.x * 128;
  const float INF = __builtin_inff();

  // ---- phase 1: load + split x into B-fragments (register-resident) ----
  // B[k = s*32 + quad*8 + j][n = col], frag element j <-> d = s*32+quad*8+j.
  short8v Bh[2][2], Bl[2][2];
#pragma unroll
  for (int pt = 0; pt < 2; ++pt) {
    const float* xp = x + (size_t)(blockBase + w * 32 + pt * 16 + col) * 64;
#pragma unroll
    for (int s = 0; s < 2; ++s) {
      const float4* src = (const float4*)(xp + s * 32 + quad * 8);
      float4 a = src[0], b = src[1];
      float xs[8] = {a.x, a.y, a.z, a.w, b.x, b.y, b.z, b.w};
      short8v hf, lf;
#pragma unroll
      for (int j = 0; j < 8; ++j) {
        u16 h = bf16rtn(xs[j]);
        hf[j] = (short)h;
        lf[j] = (short)bf16rtn(xs[j] - bf2f(h));
      }
      Bh[pt][s] = hf;
      Bl[pt][s] = lf;
    }
  }

  // running top-2 of packed biased distances, per point-tile
  float b1[2] = {INF, INF}, b2[2] = {INF, INF};

  // ---- phase 2: K loop, 8 chunks of 128 codes ----
  for (int ch = 0; ch < 8; ++ch) {
    const int kbase = ch * 128;
    __syncthreads();
    // stage chunk: global [k][64] bf16 rows -> LDS stride-72 rows
#pragma unroll
    for (int i = 0; i < 4; ++i) {
      int idx = tid + i * 256;  // 1024 x 16B per split
      int k = idx >> 3, dg = idx & 7;
      *(float4*)&hA[k * 72 + dg * 8] =
          *(const float4*)&h2g[(size_t)(kbase + k) * 64 + dg * 8];
      *(float4*)&lA[k * 72 + dg * 8] =
          *(const float4*)&l2g[(size_t)(kbase + k) * 64 + dg * 8];
    }
    if (tid < 32) *(float4*)&ecb[tid * 4] = *(const float4*)&eCb[kbase + tid * 4];
    __syncthreads();

#pragma unroll
    for (int ct = 0; ct < 8; ++ct) {  // 8 code-tiles of 16
      const int rowbase = (ct * 16 + col) * 72;  // A row m = col = code
      short8v Ah0 = *(const short8v*)&hA[rowbase + quad * 8];
      short8v Ah1 = *(const short8v*)&hA[rowbase + 32 + quad * 8];
      short8v Al0 = *(const short8v*)&lA[rowbase + quad * 8];
      short8v Al1 = *(const short8v*)&lA[rowbase + 32 + quad * 8];
      // C init = biased code norms (row = code = ct*16 + quad*4 + r)
      float4v Ci = *(const float4v*)&ecb[ct * 16 + quad * 4];
#pragma unroll
      for (int pt = 0; pt < 2; ++pt) {
        float4v C = Ci;
        C = __builtin_amdgcn_mfma_f32_16x16x32_bf16(Ah0, Bh[pt][0], C, 0, 0, 0);
        C = __builtin_amdgcn_mfma_f32_16x16x32_bf16(Ah1, Bh[pt][1], C, 0, 0, 0);
        C = __builtin_amdgcn_mfma_f32_16x16x32_bf16(Al0, Bh[pt][0], C, 0, 0, 0);
        C = __builtin_amdgcn_mfma_f32_16x16x32_bf16(Al1, Bh[pt][1], C, 0, 0, 0);
        C = __builtin_amdgcn_mfma_f32_16x16x32_bf16(Ah0, Bl[pt][0], C, 0, 0, 0);
        C = __builtin_amdgcn_mfma_f32_16x16x32_bf16(Ah1, Bl[pt][1], C, 0, 0, 0);
#pragma unroll
        for (int r = 0; r < 4; ++r) {
          // pack local id (ch:3b | ct:3b | r:2b) into low 8 mantissa bits
          u32 u = (__float_as_uint(C[r]) & 0xffffff00u) |
                  (u32)(ch * 32 + ct * 4 + r);
          float v = __uint_as_float(u);
          float pb = b1[pt];
          b1[pt] = fminf(pb, v);
          b2[pt] = med3(pb, b2[pt], v);
        }
      }
    }
  }

  // ---- phase 3: stash per-lane top-2, merge per point, gate + refine ----
  topbuf[tid * 4 + 0] = b1[0];
  topbuf[tid * 4 + 1] = b2[0];
  topbuf[tid * 4 + 2] = b1[1];
  topbuf[tid * 4 + 3] = b2[1];
  __syncthreads();

  if (tid < 128) {  // one thread per point; tid == point-in-block by construction
    const int mw = tid >> 5, mpt = (tid >> 4) & 1, mcol = tid & 15;
    float cv[8];
    int cq[8];
    float mv0 = INF, mv1 = INF;
    int q0 = 0;
#pragma unroll
    for (int q = 0; q < 4; ++q) {
      int lbase = (mw * 64 + q * 16 + mcol) * 4 + mpt * 2;
#pragma unroll
      for (int j = 0; j < 2; ++j) {
        float v = topbuf[lbase + j];
        cv[q * 2 + j] = v;
        cq[q * 2 + j] = q;
        if (v < mv0) { mv1 = mv0; mv0 = v; q0 = q; }
        else if (v < mv1) { mv1 = v; }
      }
    }
    u32 lb = __float_as_uint(mv0) & 255u;
    int bestk = (int)((lb >> 5) * 128 + ((lb >> 2) & 7) * 16 + q0 * 4 + (lb & 3));

    if (mv1 - mv0 < GATE) {
      // ----- exact emulation of the np reference's fp32 arithmetic -----
      const float* f = x + (size_t)(blockBase + tid) * 64;
      float r8[8];
#pragma unroll
      for (int j = 0; j < 8; ++j) { float fv = f[j]; r8[j] = __fmul_rn(fv, fv); }
#pragma unroll
      for (int i = 8; i < D; i += 8)
#pragma unroll
        for (int j = 0; j < 8; ++j) {
          float fv = f[i + j];
          r8[j] = __fadd_rn(r8[j], __fmul_rn(fv, fv));
        }
      float A = __fadd_rn(__fadd_rn(__fadd_rn(r8[0], r8[1]), __fadd_rn(r8[2], r8[3])),
                          __fadd_rn(__fadd_rn(r8[4], r8[5]), __fadd_rn(r8[6], r8[7])));
      float bd = INF;
      int bkk = K;
#pragma unroll
      for (int c = 0; c < 8; ++c) {
        u32 cb = __float_as_uint(cv[c]) & 255u;
        int k = (int)((cb >> 5) * 128 + ((cb >> 2) & 7) * 16 + cq[c] * 4 + (cb & 3));
        float m = 0.f;  // sequential fp32 fma over d (BLAS k-loop order)
#pragma unroll
        for (int d = 0; d < D; ++d) m = __fmaf_rn(f[d], E[d * K + k], m);
        float dist = __fadd_rn(__fsub_rn(A, __fmul_rn(2.f, m)), eC[k]);
        bool better = (dist < bd) || (dist == bd && k < bkk);
        bd = better ? dist : bd;
        bkk = better ? k : bkk;
      }
      bestk = bkk;
    }

    bkbuf[tid] = bestk;
    out[QOFF + 2 + blockBase + tid] = (float)bestk;  // index (exact as float)
    atomicAdd(&counts[bestk], 1);
  }
  __syncthreads();

  // ---- phase 4: quantized write (gather from Et, coalesced) + loss ----
  const int pp = tid >> 1, half = tid & 1;
  const int bk = bkbuf[pp];
  const float4* et = (const float4*)(Etg + (size_t)bk * 64 + half * 32);
  const float4* xr = (const float4*)(x + (size_t)(blockBase + pp) * 64 + half * 32);
  float4* ov = (float4*)(out + (size_t)(blockBase + pp) * 64 + half * 32);
  float errs = 0.f;
#pragma unroll
  for (int i = 0; i < 8; ++i) {
    float4 qv = et[i];
    float4 xv = xr[i];
    float dx;
    dx = qv.x - xv.x; errs = fmaf(dx, dx, errs);
    dx = qv.y - xv.y; errs = fmaf(dx, dx, errs);
    dx = qv.z - xv.z; errs = fmaf(dx, dx, errs);
    dx = qv.w - xv.w; errs = fmaf(dx, dx, errs);
    ov[i] = qv;
  }
  double de = (double)errs;
#pragma unroll
  for (int off = 32; off > 0; off >>= 1) de += __shfl_down(de, off, 64);
  if (lane == 0) atomicAdd(lossSum, de);
}

__global__ __launch_bounds__(256) void vq_finalize(const double* __restrict__ lossSum,
                                                   const int* __restrict__ counts,
                                                   float* __restrict__ out) {
  __shared__ double sh[256];
  double ent = 0.0;
  for (int k = threadIdx.x; k < K; k += 256) {
    double pp = (double)counts[k] / (double)NPTS;
    ent += pp * log(pp + 1e-10);
  }
  sh[threadIdx.x] = ent;
  __syncthreads();
  for (int s = 128; s > 0; s >>= 1) {
    if (threadIdx.x < s) sh[threadIdx.x] += sh[threadIdx.x + s];
    __syncthreads();
  }
  if (threadIdx.x == 0) {
    // loss = q_latent + 0.25 * e_latent = 1.25 * mean((q - x)^2)
    out[QOFF + 0] = (float)(1.25 * (*lossSum) / (double)((long)NPTS * D));
    out[QOFF + 1] = (float)exp(-sh[0]);  // perplexity
  }
}

extern "C" void kernel_launch(void* const* d_in, const int* in_sizes, int n_in,
                              void* d_out, int out_size, void* d_ws, size_t ws_size,
                              hipStream_t stream) {
  const float* x = (const float*)d_in[0];
  const float* E = (const float*)d_in[1];
  float* out = (float*)d_out;

  char* ws = (char*)d_ws;
  double* lossSum = (double*)(ws + OFF_LOSS);
  int* counts = (int*)(ws + OFF_CNT);
  float* eC = (float*)(ws + OFF_EC);
  float* eCb = (float*)(ws + OFF_ECB);
  float* Etg = (float*)(ws + OFF_ET);
  u16* h2g = (u16*)(ws + OFF_H2);
  u16* l2g = (u16*)(ws + OFF_L2);

  // ws is poisoned 0xAA before every timed launch — zero accumulators.
  hipMemsetAsync(d_ws, 0, WS_ZERO, stream);

  prep_norm<<<K / 256, 256, 0, stream>>>(E, eC, eCb);
  prep_conv<<<(K * 16) / 256, 256, 0, stream>>>(E, Etg, h2g, l2g);
  vq_main<<<NPTS / 128, 256, 0, stream>>>(x, E, h2g, l2g, eC, eCb, Etg, out,
                                          lossSum, counts);
  vq_finalize<<<1, 256, 0, stream>>>(lossSum, counts, out);
}